// Round 1
// baseline (505.245 us; speedup 1.0000x reference)
//
#include <hip/hip_runtime.h>

// BaseOpenSetClassifier: per-pixel distances to K templates + min/argmin + masks.
// B=16, N=16384, D=64, K=64, thresholds {0.5, 1.0}, N_CLASSES=21.
//
// Layout decisions:
//  - lane = (b = t&15, nl = t>>4): each wave covers 16 b x 4 n, so template
//    loads (address depends only on n) are 4-distinct-address broadcasts and
//    each template byte is fetched from HBM exactly once per block (all-b reuse
//    lives inside the wave). No LDS, no barriers.
//  - x[b][n][0..63] lives in 16 float4 registers, loaded once, reused for all K.
//  - min/argmin over k is thread-local (no cross-lane reduction); '<' keeps the
//    first k on ties, matching jnp.argmin.

#define BB 16
#define NN 16384
#define DD 64
#define KK 64
#define NT 16   // pixels (n) per block -> 256 threads, 4 waves, 1024 blocks

__global__ __launch_bounds__(256, 4)
void openset_kernel(const float* __restrict__ x,     // [B,N,D]
                    const float* __restrict__ tmpl,  // [K,N,D]
                    const int*   __restrict__ tcls,  // [K]
                    float*       __restrict__ out) { // [2*B*N | B*N | B*N]
    const int t  = threadIdx.x;
    const int b  = t & 15;
    const int nl = t >> 4;                   // 0..15
    const int n  = blockIdx.x * NT + nl;

    // x vector for this (b, n): 64 floats = 16 float4 in registers
    const float4* xp = (const float4*)(x + ((size_t)b * NN + n) * DD);
    float4 xv[16];
#pragma unroll
    for (int j = 0; j < 16; ++j) xv[j] = xp[j];

    float best  = 3.4e38f;
    int   bestk = 0;

    const float4* tbase = (const float4*)(tmpl + (size_t)n * DD);
    const size_t kstride = (size_t)NN * DD / 4;   // float4 stride between templates

#pragma unroll 1
    for (int k = 0; k < KK; ++k) {
        const float4* tk = tbase + (size_t)k * kstride;
        float s0 = 0.f, s1 = 0.f, s2 = 0.f, s3 = 0.f;
#pragma unroll
        for (int j = 0; j < 16; ++j) {
            float4 tv = tk[j];
            float d0 = xv[j].x - tv.x;
            float d1 = xv[j].y - tv.y;
            float d2 = xv[j].z - tv.z;
            float d3 = xv[j].w - tv.w;
            s0 = fmaf(d0, d0, s0);
            s1 = fmaf(d1, d1, s1);
            s2 = fmaf(d2, d2, s2);
            s3 = fmaf(d3, d3, s3);
        }
        float dist = (s0 + s1) + (s2 + s3);
        if (dist < best) { best = dist; bestk = k; }
    }

    const size_t BN = (size_t)BB * NN;
    const size_t o  = (size_t)b * NN + n;
    out[o]             = (best <= 0.5f) ? 1.0f : 0.0f;  // masks[0]
    out[BN + o]        = (best <= 1.0f) ? 1.0f : 0.0f;  // masks[1]
    out[2 * BN + o]    = best;                          // min_dists
    out[3 * BN + o]    = (float)tcls[bestk];            // pred_classes
}

extern "C" void kernel_launch(void* const* d_in, const int* in_sizes, int n_in,
                              void* d_out, int out_size, void* d_ws, size_t ws_size,
                              hipStream_t stream) {
    const float* x    = (const float*)d_in[0];   // frame_embeddings [16,16384,64]
    const float* tmpl = (const float*)d_in[1];   // templates       [64,16384,64]
    const int*   tcls = (const int*)d_in[2];     // template_classes [64]
    float* out = (float*)d_out;

    dim3 grid(NN / NT);   // 1024
    dim3 block(256);
    openset_kernel<<<grid, block, 0, stream>>>(x, tmpl, tcls, out);
}